// Round 1
// baseline (987.573 us; speedup 1.0000x reference)
//
#include <hip/hip_runtime.h>

// Problem constants (match reference)
#define N_NODES 100000
#define IN_C    128
#define HID_C   64
#define OUT_C   40
#define N_EDGES 1600000

// ---------------------------------------------------------------------------
// deg / dinv
// ---------------------------------------------------------------------------
__global__ void k_init_deg(float* __restrict__ deg) {
    int i = blockIdx.x * blockDim.x + threadIdx.x;
    if (i < N_NODES) deg[i] = 1.0f;  // self-loop counts once
}

__global__ void k_count_deg(const int* __restrict__ dst, float* __restrict__ deg) {
    int e = blockIdx.x * blockDim.x + threadIdx.x;
    if (e < N_EDGES) atomicAdd(&deg[dst[e]], 1.0f);
}

__global__ void k_deg_to_dinv(float* __restrict__ deg) {
    int i = blockIdx.x * blockDim.x + threadIdx.x;
    if (i < N_NODES) deg[i] = 1.0f / sqrtf(deg[i]);  // deg >= 1 always
}

// ---------------------------------------------------------------------------
// Skinny GEMM: out[row, c] = sum_k f(in[row, k]) * W[k, c]
// One wave per row; lane < OUT computes one output channel.
// in-row loads are wave-broadcast (same addr all lanes); W loads coalesced.
// ---------------------------------------------------------------------------
template <int K, int OUT, bool RELU>
__global__ void k_gemm(const float* __restrict__ in, const float* __restrict__ W,
                       float* __restrict__ out) {
    int wid  = (blockIdx.x * blockDim.x + threadIdx.x) >> 6;  // wave id = row
    int lane = threadIdx.x & 63;
    if (wid >= N_NODES) return;
    const float* row = in + (size_t)wid * K;
    if (lane < OUT) {
        float acc = 0.0f;
#pragma unroll 8
        for (int k = 0; k < K; ++k) {
            float v = row[k];
            if (RELU) v = fmaxf(v, 0.0f);
            acc += v * W[k * OUT + lane];
        }
        out[(size_t)wid * OUT + lane] = acc;
    }
}

// ---------------------------------------------------------------------------
// Aggregation-buffer init: agg[n, c] = b[c] + h[n, c] * dinv[n]^2
// (fuses bias and the self-loop message; self-loop norm = dinv^2 = 1/deg)
// ---------------------------------------------------------------------------
template <int C>
__global__ void k_init_agg(const float* __restrict__ h, const float* __restrict__ dinv,
                           const float* __restrict__ b, float* __restrict__ agg) {
    int t = blockIdx.x * blockDim.x + threadIdx.x;
    if (t >= N_NODES * C) return;
    int n = t / C;
    int c = t - n * C;
    float di = dinv[n];
    agg[t] = b[c] + h[t] * (di * di);
}

// ---------------------------------------------------------------------------
// Edge scatter (push): agg[dst, c] += h[src, c] * dinv[src] * dinv[dst]
// One wave per edge, lane = channel (lanes >= C idle for C=40).
// ---------------------------------------------------------------------------
template <int C>
__global__ void k_scatter(const int* __restrict__ src, const int* __restrict__ dst,
                          const float* __restrict__ dinv, const float* __restrict__ h,
                          float* __restrict__ agg) {
    long long t = (long long)blockIdx.x * blockDim.x + threadIdx.x;
    int e = (int)(t >> 6);
    int c = (int)(t & 63);
    if (e >= N_EDGES || c >= C) return;
    int s = src[e];
    int d = dst[e];
    float norm = dinv[s] * dinv[d];
    atomicAdd(&agg[(size_t)d * C + c], h[(size_t)s * C + c] * norm);
}

// ---------------------------------------------------------------------------
// launch
// ---------------------------------------------------------------------------
extern "C" void kernel_launch(void* const* d_in, const int* in_sizes, int n_in,
                              void* d_out, int out_size, void* d_ws, size_t ws_size,
                              hipStream_t stream) {
    const float* x   = (const float*)d_in[0];
    const int*   ei  = (const int*)d_in[1];
    const int*   src = ei;             // edge_index[0]
    const int*   dst = ei + N_EDGES;   // edge_index[1]
    const float* W1  = (const float*)d_in[2];
    const float* b1  = (const float*)d_in[3];
    const float* W2  = (const float*)d_in[4];
    const float* b2  = (const float*)d_in[5];
    float*       out = (float*)d_out;

    // workspace layout (floats)
    float* dinv = (float*)d_ws;                      // N          (deg, then dinv)
    float* h1   = dinv + N_NODES;                    // N*HID_C
    float* agg1 = h1 + (size_t)N_NODES * HID_C;      // N*HID_C
    float* h2   = h1;                                // reuse h1 region (N*OUT_C <= N*HID_C)

    const int B = 256;

    // degrees -> dinv
    k_init_deg<<<(N_NODES + B - 1) / B, B, 0, stream>>>(dinv);
    k_count_deg<<<(N_EDGES + B - 1) / B, B, 0, stream>>>(dst, dinv);
    k_deg_to_dinv<<<(N_NODES + B - 1) / B, B, 0, stream>>>(dinv);

    // layer 1: h1 = x @ W1
    {
        long long threads = (long long)N_NODES * 64;
        k_gemm<IN_C, HID_C, false><<<(int)((threads + B - 1) / B), B, 0, stream>>>(x, W1, h1);
    }
    // agg1 = b1 + self-loop; then scatter edges
    k_init_agg<HID_C><<<(N_NODES * HID_C + B - 1) / B, B, 0, stream>>>(h1, dinv, b1, agg1);
    {
        long long threads = (long long)N_EDGES * 64;
        k_scatter<HID_C><<<(int)((threads + B - 1) / B), B, 0, stream>>>(src, dst, dinv, h1, agg1);
    }

    // layer 2: h2 = relu(agg1) @ W2
    {
        long long threads = (long long)N_NODES * 64;
        k_gemm<HID_C, OUT_C, true><<<(int)((threads + B - 1) / B), B, 0, stream>>>(agg1, W2, h2);
    }
    // out = b2 + self-loop; then scatter edges
    k_init_agg<OUT_C><<<(N_NODES * OUT_C + B - 1) / B, B, 0, stream>>>(h2, dinv, b2, out);
    {
        long long threads = (long long)N_EDGES * 64;
        k_scatter<OUT_C><<<(int)((threads + B - 1) / B), B, 0, stream>>>(src, dst, dinv, h2, out);
    }
}

// Round 2
// 465.567 us; speedup vs baseline: 2.1212x; 2.1212x over previous
//
#include <hip/hip_runtime.h>

#define N_NODES 100000
#define IN_C    128
#define HID_C   64
#define OUT_C   40
#define N_EDGES 1600000

#define SCAN_ITEMS 1024                         // items per scan block
#define NB ((N_NODES + SCAN_ITEMS - 1) / SCAN_ITEMS)   // 98

// ---------------------------------------------------------------------------
// zero counts
// ---------------------------------------------------------------------------
__global__ void k_zero(int* __restrict__ p, int n) {
    int i = blockIdx.x * blockDim.x + threadIdx.x;
    if (i < n) p[i] = 0;
}

// counts[dst]++ (int atomics)
__global__ void k_count(const int* __restrict__ dst, int* __restrict__ cnt) {
    int e = blockIdx.x * blockDim.x + threadIdx.x;
    if (e < N_EDGES) atomicAdd(&cnt[dst[e]], 1);
}

// ---------------------------------------------------------------------------
// 3-phase exclusive scan of cnt -> cursor (row starts); blks = block sums
// ---------------------------------------------------------------------------
__global__ void k_scan_blk(const int* __restrict__ cnt, int* __restrict__ cursor,
                           int* __restrict__ blks) {
    __shared__ int s[256];
    int tid = threadIdx.x;
    int base = blockIdx.x * SCAN_ITEMS + tid * 4;
    int a0 = (base + 0 < N_NODES) ? cnt[base + 0] : 0;
    int a1 = (base + 1 < N_NODES) ? cnt[base + 1] : 0;
    int a2 = (base + 2 < N_NODES) ? cnt[base + 2] : 0;
    int a3 = (base + 3 < N_NODES) ? cnt[base + 3] : 0;
    int tsum = a0 + a1 + a2 + a3;
    s[tid] = tsum;
    __syncthreads();
    for (int off = 1; off < 256; off <<= 1) {
        int t = (tid >= off) ? s[tid - off] : 0;
        __syncthreads();
        s[tid] += t;
        __syncthreads();
    }
    int texcl = s[tid] - tsum;
    if (base + 0 < N_NODES) cursor[base + 0] = texcl;
    if (base + 1 < N_NODES) cursor[base + 1] = texcl + a0;
    if (base + 2 < N_NODES) cursor[base + 2] = texcl + a0 + a1;
    if (base + 3 < N_NODES) cursor[base + 3] = texcl + a0 + a1 + a2;
    if (tid == 0) blks[blockIdx.x] = s[255];
}

__global__ void k_scan_top(int* __restrict__ blks) {
    __shared__ int s[128];
    int tid = threadIdx.x;  // 128 threads
    int v = (tid < NB) ? blks[tid] : 0;
    s[tid] = v;
    __syncthreads();
    for (int off = 1; off < 128; off <<= 1) {
        int t = (tid >= off) ? s[tid - off] : 0;
        __syncthreads();
        s[tid] += t;
        __syncthreads();
    }
    if (tid < NB) blks[tid] = s[tid] - v;  // exclusive
}

// add block offsets; also compute dinv = rsqrt(deg) with deg = cnt + 1 (self-loop)
__global__ void k_scan_add(const int* __restrict__ cnt, int* __restrict__ cursor,
                           const int* __restrict__ blks, float* __restrict__ dinv) {
    int tid = threadIdx.x;
    int base = blockIdx.x * SCAN_ITEMS + tid * 4;
    int off = blks[blockIdx.x];
#pragma unroll
    for (int j = 0; j < 4; ++j) {
        int i = base + j;
        if (i < N_NODES) {
            cursor[i] += off;
            dinv[i] = rsqrtf(1.0f + (float)cnt[i]);
        }
    }
}

// fill CSR: esrc[pos] = src, pos allocated by bumping cursor[dst]
__global__ void k_fill(const int* __restrict__ src, const int* __restrict__ dst,
                       int* __restrict__ cursor, int* __restrict__ esrc) {
    int e = blockIdx.x * blockDim.x + threadIdx.x;
    if (e < N_EDGES) {
        int pos = atomicAdd(&cursor[dst[e]], 1);
        esrc[pos] = src[e];
    }
}
// post-fill: cursor[n] == end of row n; start(n) = n ? cursor[n-1] : 0

// ---------------------------------------------------------------------------
// g1[n,c] = dinv[n] * (x[n,:] @ W1)[c]    (wave per row, LDS-staged row)
// ---------------------------------------------------------------------------
__global__ void k_gemm1(const float* __restrict__ x, const float* __restrict__ W1,
                        const float* __restrict__ dinv, float* __restrict__ g1) {
    __shared__ float srow[4][IN_C];
    int w    = threadIdx.x >> 6;
    int lane = threadIdx.x & 63;
    int row  = blockIdx.x * 4 + w;          // N_NODES % 4 == 0
    const float* rp = x + (size_t)row * IN_C;
    srow[w][lane]      = rp[lane];
    srow[w][lane + 64] = rp[lane + 64];
    float acc = 0.0f;
#pragma unroll 16
    for (int k = 0; k < IN_C; ++k)
        acc += srow[w][k] * W1[k * HID_C + lane];
    g1[(size_t)row * HID_C + lane] = dinv[row] * acc;
}

// ---------------------------------------------------------------------------
// pull layer1 + fused 64->40 GEMM:
//   acc[c]  = g1[n,c] + sum_{e in row n} g1[src_e, c]
//   r[c]    = relu(dinv[n]*acc[c] + b1[c])
//   g2[n,o] = dinv[n] * sum_c r[c] * W2[c,o]
// ---------------------------------------------------------------------------
__global__ void k_pull1(const int* __restrict__ cursor, const int* __restrict__ esrc,
                        const float* __restrict__ dinv, const float* __restrict__ g1,
                        const float* __restrict__ b1, const float* __restrict__ W2,
                        float* __restrict__ g2) {
    __shared__ float lds[4][HID_C];
    int w    = threadIdx.x >> 6;
    int lane = threadIdx.x & 63;
    int n    = blockIdx.x * 4 + w;
    float dn  = dinv[n];
    int start = n ? cursor[n - 1] : 0;
    int end   = cursor[n];
    float acc = g1[(size_t)n * HID_C + lane];
    int e = start;
    for (; e + 3 < end; e += 4) {
        int s0 = esrc[e], s1 = esrc[e + 1], s2 = esrc[e + 2], s3 = esrc[e + 3];
        float v0 = g1[(size_t)s0 * HID_C + lane];
        float v1 = g1[(size_t)s1 * HID_C + lane];
        float v2 = g1[(size_t)s2 * HID_C + lane];
        float v3 = g1[(size_t)s3 * HID_C + lane];
        acc += v0 + v1 + v2 + v3;
    }
    for (; e < end; ++e)
        acc += g1[(size_t)esrc[e] * HID_C + lane];
    float r = fmaxf(dn * acc + b1[lane], 0.0f);
    lds[w][lane] = r;
    // wave-private LDS; same-wave write->read ordering handled by compiler waits
    if (lane < OUT_C) {
        float s = 0.0f;
#pragma unroll
        for (int c = 0; c < HID_C; ++c)
            s += lds[w][c] * W2[c * OUT_C + lane];
        g2[(size_t)n * OUT_C + lane] = dn * s;
    }
}

// ---------------------------------------------------------------------------
// pull layer2: out[n,o] = b2[o] + dinv[n] * (g2[n,o] + sum_e g2[src_e, o])
// ---------------------------------------------------------------------------
__global__ void k_pull2(const int* __restrict__ cursor, const int* __restrict__ esrc,
                        const float* __restrict__ dinv, const float* __restrict__ g2,
                        const float* __restrict__ b2, float* __restrict__ out) {
    int w    = threadIdx.x >> 6;
    int lane = threadIdx.x & 63;
    int n    = blockIdx.x * 4 + w;
    if (lane >= OUT_C) return;
    float dn  = dinv[n];
    int start = n ? cursor[n - 1] : 0;
    int end   = cursor[n];
    float acc = g2[(size_t)n * OUT_C + lane];
    int e = start;
    for (; e + 3 < end; e += 4) {
        int s0 = esrc[e], s1 = esrc[e + 1], s2 = esrc[e + 2], s3 = esrc[e + 3];
        float v0 = g2[(size_t)s0 * OUT_C + lane];
        float v1 = g2[(size_t)s1 * OUT_C + lane];
        float v2 = g2[(size_t)s2 * OUT_C + lane];
        float v3 = g2[(size_t)s3 * OUT_C + lane];
        acc += v0 + v1 + v2 + v3;
    }
    for (; e < end; ++e)
        acc += g2[(size_t)esrc[e] * OUT_C + lane];
    out[(size_t)n * OUT_C + lane] = b2[lane] + dn * acc;
}

// ---------------------------------------------------------------------------
// launch
// ---------------------------------------------------------------------------
extern "C" void kernel_launch(void* const* d_in, const int* in_sizes, int n_in,
                              void* d_out, int out_size, void* d_ws, size_t ws_size,
                              hipStream_t stream) {
    const float* x   = (const float*)d_in[0];
    const int*   ei  = (const int*)d_in[1];
    const int*   src = ei;
    const int*   dst = ei + N_EDGES;
    const float* W1  = (const float*)d_in[2];
    const float* b1  = (const float*)d_in[3];
    const float* W2  = (const float*)d_in[4];
    const float* b2  = (const float*)d_in[5];
    float*       out = (float*)d_out;

    // workspace layout (4-byte units), total ~49.2 MB
    int*   cnt    = (int*)d_ws;                         // N
    int*   cursor = cnt + N_NODES;                      // N
    int*   blks   = cursor + N_NODES;                   // 128
    float* dinv   = (float*)(blks + 128);               // N
    int*   esrc   = (int*)(dinv + N_NODES);             // E
    float* g1     = (float*)(esrc + N_EDGES);           // N*HID_C
    float* g2     = g1 + (size_t)N_NODES * HID_C;       // N*OUT_C

    const int B = 256;

    // CSR build
    k_zero<<<(N_NODES + B - 1) / B, B, 0, stream>>>(cnt, N_NODES);
    k_count<<<(N_EDGES + B - 1) / B, B, 0, stream>>>(dst, cnt);
    k_scan_blk<<<NB, 256, 0, stream>>>(cnt, cursor, blks);
    k_scan_top<<<1, 128, 0, stream>>>(blks);
    k_scan_add<<<NB, 256, 0, stream>>>(cnt, cursor, blks, dinv);
    k_fill<<<(N_EDGES + B - 1) / B, B, 0, stream>>>(src, dst, cursor, esrc);

    // layer 1 transform (scaled): g1 = dinv * (x @ W1)
    k_gemm1<<<N_NODES / 4, 256, 0, stream>>>(x, W1, dinv, g1);

    // pull-aggregate layer 1 + fused GEMM2: g2 = dinv * (relu(agg1) @ W2)
    k_pull1<<<N_NODES / 4, 256, 0, stream>>>(cursor, esrc, dinv, g1, b1, W2, g2);

    // pull-aggregate layer 2 -> out
    k_pull2<<<N_NODES / 4, 256, 0, stream>>>(cursor, esrc, dinv, g2, b2, out);
}

// Round 3
// 326.611 us; speedup vs baseline: 3.0237x; 1.4255x over previous
//
#include <hip/hip_runtime.h>

#define N_NODES 100000
#define IN_C    128
#define HID_C   64
#define OUT_C   40
#define N_EDGES 1600000

// bucketed CSR build
#define BSH        8
#define NBUCK      ((N_NODES + 255) >> BSH)              // 391 buckets of 256 nodes
#define PART_CHUNK 4096                                  // edges per partition block
#define NPB        ((N_EDGES + PART_CHUNK - 1) / PART_CHUNK)  // 391
#define EPT        (PART_CHUNK / 256)                    // 16 edges per thread

// node-count scan
#define SCAN_ITEMS 1024
#define NB ((N_NODES + SCAN_ITEMS - 1) / SCAN_ITEMS)     // 98

typedef _Float16 half_t;

// ---------------------------------------------------------------------------
// bucket histogram + scan
// ---------------------------------------------------------------------------
__global__ void k_zero_bcnt(int* __restrict__ bcnt) {
    int i = threadIdx.x;
    if (i < NBUCK) bcnt[i] = 0;
}

__global__ void k_hist(const int* __restrict__ dst, int* __restrict__ bcnt) {
    __shared__ int lh[NBUCK];
    int tid = threadIdx.x;
    for (int i = tid; i < NBUCK; i += 256) lh[i] = 0;
    __syncthreads();
    int base = blockIdx.x * PART_CHUNK;
#pragma unroll
    for (int j = 0; j < EPT; ++j) {
        int e = base + j * 256 + tid;
        if (e < N_EDGES) atomicAdd(&lh[dst[e] >> BSH], 1);
    }
    __syncthreads();
    for (int i = tid; i < NBUCK; i += 256)
        if (lh[i]) atomicAdd(&bcnt[i], lh[i]);
}

__global__ void k_bscan(const int* __restrict__ bcnt, int* __restrict__ bstart,
                        int* __restrict__ gcur) {
    __shared__ int s[512];
    int tid = threadIdx.x;
    int v = (tid < NBUCK) ? bcnt[tid] : 0;
    s[tid] = v;
    __syncthreads();
    for (int off = 1; off < 512; off <<= 1) {
        int t = (tid >= off) ? s[tid - off] : 0;
        __syncthreads();
        s[tid] += t;
        __syncthreads();
    }
    if (tid < NBUCK) {
        int excl = s[tid] - v;
        bstart[tid] = excl;
        gcur[tid]   = excl;
    }
    if (tid == 0) bstart[NBUCK] = N_EDGES;
}

// ---------------------------------------------------------------------------
// partition edges into bucket order (LDS-ranked, pair-packed 8B writes)
// ---------------------------------------------------------------------------
__global__ void k_part(const int* __restrict__ src, const int* __restrict__ dst,
                       int* __restrict__ gcur, unsigned long long* __restrict__ pairs) {
    __shared__ int lh[NBUCK];
    int tid = threadIdx.x;
    for (int i = tid; i < NBUCK; i += 256) lh[i] = 0;
    __syncthreads();
    int base = blockIdx.x * PART_CHUNK;
    int sv[EPT], dv[EPT], rv[EPT];
#pragma unroll
    for (int j = 0; j < EPT; ++j) {
        int e = base + j * 256 + tid;
        if (e < N_EDGES) {
            sv[j] = src[e];
            dv[j] = dst[e];
            rv[j] = atomicAdd(&lh[dv[j] >> BSH], 1);
        } else {
            dv[j] = -1;
        }
    }
    __syncthreads();
    for (int i = tid; i < NBUCK; i += 256) {
        int c = lh[i];
        if (c) lh[i] = atomicAdd(&gcur[i], c);
    }
    __syncthreads();
#pragma unroll
    for (int j = 0; j < EPT; ++j) {
        if (dv[j] >= 0) {
            int pos = lh[dv[j] >> BSH] + rv[j];
            pairs[pos] = ((unsigned long long)(unsigned)dv[j] << 32) | (unsigned)sv[j];
        }
    }
}

// ---------------------------------------------------------------------------
// per-bucket node counts (LDS atomics only, coalesced cnt writes)
// ---------------------------------------------------------------------------
__global__ void k_bcount(const unsigned long long* __restrict__ pairs,
                         const int* __restrict__ bstart, int* __restrict__ cnt) {
    __shared__ int lc[256];
    int b = blockIdx.x, tid = threadIdx.x;
    lc[tid] = 0;
    __syncthreads();
    int s0 = bstart[b], s1 = bstart[b + 1];
    int nbase = b << BSH;
    for (int e = s0 + tid; e < s1; e += 256)
        atomicAdd(&lc[(int)(pairs[e] >> 32) - nbase], 1);
    __syncthreads();
    int node = nbase + tid;
    if (node < N_NODES) cnt[node] = lc[tid];
}

// ---------------------------------------------------------------------------
// exclusive scan of cnt -> cursor (row starts); dinv = rsqrt(1+cnt)
// ---------------------------------------------------------------------------
__global__ void k_scan_blk(const int* __restrict__ cnt, int* __restrict__ cursor,
                           int* __restrict__ blks) {
    __shared__ int s[256];
    int tid = threadIdx.x;
    int base = blockIdx.x * SCAN_ITEMS + tid * 4;
    int a0 = (base + 0 < N_NODES) ? cnt[base + 0] : 0;
    int a1 = (base + 1 < N_NODES) ? cnt[base + 1] : 0;
    int a2 = (base + 2 < N_NODES) ? cnt[base + 2] : 0;
    int a3 = (base + 3 < N_NODES) ? cnt[base + 3] : 0;
    int tsum = a0 + a1 + a2 + a3;
    s[tid] = tsum;
    __syncthreads();
    for (int off = 1; off < 256; off <<= 1) {
        int t = (tid >= off) ? s[tid - off] : 0;
        __syncthreads();
        s[tid] += t;
        __syncthreads();
    }
    int texcl = s[tid] - tsum;
    if (base + 0 < N_NODES) cursor[base + 0] = texcl;
    if (base + 1 < N_NODES) cursor[base + 1] = texcl + a0;
    if (base + 2 < N_NODES) cursor[base + 2] = texcl + a0 + a1;
    if (base + 3 < N_NODES) cursor[base + 3] = texcl + a0 + a1 + a2;
    if (tid == 0) blks[blockIdx.x] = s[255];
}

__global__ void k_scan_top(int* __restrict__ blks) {
    __shared__ int s[128];
    int tid = threadIdx.x;
    int v = (tid < NB) ? blks[tid] : 0;
    s[tid] = v;
    __syncthreads();
    for (int off = 1; off < 128; off <<= 1) {
        int t = (tid >= off) ? s[tid - off] : 0;
        __syncthreads();
        s[tid] += t;
        __syncthreads();
    }
    if (tid < NB) blks[tid] = s[tid] - v;
}

__global__ void k_scan_add(const int* __restrict__ cnt, int* __restrict__ cursor,
                           const int* __restrict__ blks, float* __restrict__ dinv) {
    int tid = threadIdx.x;
    int base = blockIdx.x * SCAN_ITEMS + tid * 4;
    int off = blks[blockIdx.x];
#pragma unroll
    for (int j = 0; j < 4; ++j) {
        int i = base + j;
        if (i < N_NODES) {
            cursor[i] += off;
            dinv[i] = rsqrtf(1.0f + (float)cnt[i]);
        }
    }
}

// ---------------------------------------------------------------------------
// per-bucket CSR fill (LDS cursors, L2-local esrc writes)
// ---------------------------------------------------------------------------
__global__ void k_bfill(const unsigned long long* __restrict__ pairs,
                        const int* __restrict__ bstart, const int* __restrict__ cursor,
                        int* __restrict__ esrc) {
    __shared__ int lcur[256];
    int b = blockIdx.x, tid = threadIdx.x;
    int nbase = b << BSH;
    int node = nbase + tid;
    lcur[tid] = (node < N_NODES) ? cursor[node] : 0;
    __syncthreads();
    int s0 = bstart[b], s1 = bstart[b + 1];
    for (int e = s0 + tid; e < s1; e += 256) {
        unsigned long long p = pairs[e];
        int d = (int)(p >> 32);
        int s = (int)(p & 0xffffffffu);
        int pos = atomicAdd(&lcur[d - nbase], 1);
        esrc[pos] = s;
    }
}

// ---------------------------------------------------------------------------
// g1[n,c] = dinv[n] * (x[n,:] @ W1)[c]   (fp32 math, fp16 store)
// ---------------------------------------------------------------------------
__global__ void k_gemm1(const float* __restrict__ x, const float* __restrict__ W1,
                        const float* __restrict__ dinv, half_t* __restrict__ g1) {
    __shared__ float srow[4][IN_C];
    int w    = threadIdx.x >> 6;
    int lane = threadIdx.x & 63;
    int row  = blockIdx.x * 4 + w;
    const float* rp = x + (size_t)row * IN_C;
    srow[w][lane]      = rp[lane];
    srow[w][lane + 64] = rp[lane + 64];
    float acc = 0.0f;
#pragma unroll 16
    for (int k = 0; k < IN_C; ++k)
        acc += srow[w][k] * W1[k * HID_C + lane];
    g1[(size_t)row * HID_C + lane] = (half_t)(dinv[row] * acc);
}

// ---------------------------------------------------------------------------
// pull layer1 + fused 64->40 GEMM (fp16 gathers, fp32 math)
// ---------------------------------------------------------------------------
__global__ void k_pull1(const int* __restrict__ cursor, const int* __restrict__ cnt,
                        const int* __restrict__ esrc, const float* __restrict__ dinv,
                        const half_t* __restrict__ g1, const float* __restrict__ b1,
                        const float* __restrict__ W2, half_t* __restrict__ g2) {
    __shared__ float lds[4][HID_C];
    int w    = threadIdx.x >> 6;
    int lane = threadIdx.x & 63;
    int n    = blockIdx.x * 4 + w;
    float dn  = dinv[n];
    int start = cursor[n];
    int end   = start + cnt[n];
    float acc = (float)g1[(size_t)n * HID_C + lane];
    int e = start;
    for (; e + 3 < end; e += 4) {
        int s0 = esrc[e], s1 = esrc[e + 1], s2 = esrc[e + 2], s3 = esrc[e + 3];
        float v0 = (float)g1[(size_t)s0 * HID_C + lane];
        float v1 = (float)g1[(size_t)s1 * HID_C + lane];
        float v2 = (float)g1[(size_t)s2 * HID_C + lane];
        float v3 = (float)g1[(size_t)s3 * HID_C + lane];
        acc += v0 + v1 + v2 + v3;
    }
    for (; e < end; ++e)
        acc += (float)g1[(size_t)esrc[e] * HID_C + lane];
    float r = fmaxf(dn * acc + b1[lane], 0.0f);
    lds[w][lane] = r;  // wave-private; same-wave ds ordering handled by compiler
    if (lane < OUT_C) {
        float s = 0.0f;
#pragma unroll
        for (int c = 0; c < HID_C; ++c)
            s += lds[w][c] * W2[c * OUT_C + lane];
        g2[(size_t)n * OUT_C + lane] = (half_t)(dn * s);
    }
}

// ---------------------------------------------------------------------------
// pull layer2 -> out (fp32)
// ---------------------------------------------------------------------------
__global__ void k_pull2(const int* __restrict__ cursor, const int* __restrict__ cnt,
                        const int* __restrict__ esrc, const float* __restrict__ dinv,
                        const half_t* __restrict__ g2, const float* __restrict__ b2,
                        float* __restrict__ out) {
    int w    = threadIdx.x >> 6;
    int lane = threadIdx.x & 63;
    int n    = blockIdx.x * 4 + w;
    if (lane >= OUT_C) return;
    float dn  = dinv[n];
    int start = cursor[n];
    int end   = start + cnt[n];
    float acc = (float)g2[(size_t)n * OUT_C + lane];
    int e = start;
    for (; e + 3 < end; e += 4) {
        int s0 = esrc[e], s1 = esrc[e + 1], s2 = esrc[e + 2], s3 = esrc[e + 3];
        float v0 = (float)g2[(size_t)s0 * OUT_C + lane];
        float v1 = (float)g2[(size_t)s1 * OUT_C + lane];
        float v2 = (float)g2[(size_t)s2 * OUT_C + lane];
        float v3 = (float)g2[(size_t)s3 * OUT_C + lane];
        acc += v0 + v1 + v2 + v3;
    }
    for (; e < end; ++e)
        acc += (float)g2[(size_t)esrc[e] * OUT_C + lane];
    out[(size_t)n * OUT_C + lane] = b2[lane] + dn * acc;
}

// ---------------------------------------------------------------------------
// launch
// ---------------------------------------------------------------------------
extern "C" void kernel_launch(void* const* d_in, const int* in_sizes, int n_in,
                              void* d_out, int out_size, void* d_ws, size_t ws_size,
                              hipStream_t stream) {
    const float* x   = (const float*)d_in[0];
    const int*   ei  = (const int*)d_in[1];
    const int*   src = ei;
    const int*   dst = ei + N_EDGES;
    const float* W1  = (const float*)d_in[2];
    const float* b1  = (const float*)d_in[3];
    const float* W2  = (const float*)d_in[4];
    const float* b2  = (const float*)d_in[5];
    float*       out = (float*)d_out;

    // workspace layout (~28.5 MB)
    int*   cnt    = (int*)d_ws;                       // N
    int*   cursor = cnt + N_NODES;                    // N
    int*   blks   = cursor + N_NODES;                 // 128
    int*   bcnt   = blks + 128;                       // NBUCK
    int*   bstart = bcnt + NBUCK;                     // NBUCK+1
    int*   gcur   = bstart + NBUCK + 1;               // NBUCK
    float* dinv   = (float*)(gcur + NBUCK);           // N
    int*   esrc   = (int*)(dinv + N_NODES);           // E
    int*   after  = esrc + N_EDGES;
    unsigned long long* pairs =
        (unsigned long long*)(((uintptr_t)after + 7) & ~(uintptr_t)7);  // E * 8B
    half_t* g1 = (half_t*)pairs;                      // overlays pairs (used after)
    half_t* g2 = (half_t*)(pairs + N_EDGES);          // N*OUT_C halves

    // CSR build (bucketed)
    k_zero_bcnt<<<1, 512, 0, stream>>>(bcnt);
    k_hist<<<NPB, 256, 0, stream>>>(dst, bcnt);
    k_bscan<<<1, 512, 0, stream>>>(bcnt, bstart, gcur);
    k_part<<<NPB, 256, 0, stream>>>(src, dst, gcur, pairs);
    k_bcount<<<NBUCK, 256, 0, stream>>>(pairs, bstart, cnt);
    k_scan_blk<<<NB, 256, 0, stream>>>(cnt, cursor, blks);
    k_scan_top<<<1, 128, 0, stream>>>(blks);
    k_scan_add<<<NB, 256, 0, stream>>>(cnt, cursor, blks, dinv);
    k_bfill<<<NBUCK, 256, 0, stream>>>(pairs, bstart, cursor, esrc);

    // layer 1 transform: g1 = dinv * (x @ W1)  [fp16]
    k_gemm1<<<N_NODES / 4, 256, 0, stream>>>(x, W1, dinv, g1);

    // pull layer 1 + fused GEMM2
    k_pull1<<<N_NODES / 4, 256, 0, stream>>>(cursor, cnt, esrc, dinv, g1, b1, W2, g2);

    // pull layer 2
    k_pull2<<<N_NODES / 4, 256, 0, stream>>>(cursor, cnt, esrc, dinv, g2, b2, out);
}

// Round 4
// 253.031 us; speedup vs baseline: 3.9030x; 1.2908x over previous
//
#include <hip/hip_runtime.h>

#define N_NODES 100000
#define IN_C    128
#define HID_C   64
#define OUT_C   40
#define N_EDGES 1600000

// bucketed CSR build
#define BSH        8
#define NBUCK      ((N_NODES + 255) >> BSH)              // 391 buckets of 256 nodes
#define PART_CHUNK 4096
#define NPB        ((N_EDGES + PART_CHUNK - 1) / PART_CHUNK)  // 391
#define EPT        (PART_CHUNK / 256)

// node-count scan
#define SCAN_ITEMS 1024
#define NB ((N_NODES + SCAN_ITEMS - 1) / SCAN_ITEMS)     // 98

typedef _Float16 half_t;
typedef _Float16 half8 __attribute__((ext_vector_type(8)));
typedef float    f32x4 __attribute__((ext_vector_type(4)));

// ---------------------------------------------------------------------------
// init: zero bucket counts + transpose W1 -> W1T [64][128] fp16
// ---------------------------------------------------------------------------
__global__ void k_init(const float* __restrict__ W1, half_t* __restrict__ W1T,
                       int* __restrict__ bcnt) {
    int t = threadIdx.x;  // 512
    if (t < NBUCK) bcnt[t] = 0;
    for (int i = t; i < IN_C * HID_C; i += 512) {
        int k = i >> 6, n = i & 63;
        W1T[n * IN_C + k] = (half_t)W1[i];
    }
}

__global__ void k_hist(const int* __restrict__ dst, int* __restrict__ bcnt) {
    __shared__ int lh[NBUCK];
    int tid = threadIdx.x;
    for (int i = tid; i < NBUCK; i += 256) lh[i] = 0;
    __syncthreads();
    int base = blockIdx.x * PART_CHUNK;
#pragma unroll
    for (int j = 0; j < EPT; ++j) {
        int e = base + j * 256 + tid;
        if (e < N_EDGES) atomicAdd(&lh[dst[e] >> BSH], 1);
    }
    __syncthreads();
    for (int i = tid; i < NBUCK; i += 256)
        if (lh[i]) atomicAdd(&bcnt[i], lh[i]);
}

__global__ void k_bscan(const int* __restrict__ bcnt, int* __restrict__ bstart,
                        int* __restrict__ gcur) {
    __shared__ int s[512];
    int tid = threadIdx.x;
    int v = (tid < NBUCK) ? bcnt[tid] : 0;
    s[tid] = v;
    __syncthreads();
    for (int off = 1; off < 512; off <<= 1) {
        int t = (tid >= off) ? s[tid - off] : 0;
        __syncthreads();
        s[tid] += t;
        __syncthreads();
    }
    if (tid < NBUCK) {
        int excl = s[tid] - v;
        bstart[tid] = excl;
        gcur[tid]   = excl;
    }
    if (tid == 0) bstart[NBUCK] = N_EDGES;
}

__global__ void k_part(const int* __restrict__ src, const int* __restrict__ dst,
                       int* __restrict__ gcur, unsigned long long* __restrict__ pairs) {
    __shared__ int lh[NBUCK];
    int tid = threadIdx.x;
    for (int i = tid; i < NBUCK; i += 256) lh[i] = 0;
    __syncthreads();
    int base = blockIdx.x * PART_CHUNK;
    int sv[EPT], dv[EPT], rv[EPT];
#pragma unroll
    for (int j = 0; j < EPT; ++j) {
        int e = base + j * 256 + tid;
        if (e < N_EDGES) {
            sv[j] = src[e];
            dv[j] = dst[e];
            rv[j] = atomicAdd(&lh[dv[j] >> BSH], 1);
        } else {
            dv[j] = -1;
        }
    }
    __syncthreads();
    for (int i = tid; i < NBUCK; i += 256) {
        int c = lh[i];
        if (c) lh[i] = atomicAdd(&gcur[i], c);
    }
    __syncthreads();
#pragma unroll
    for (int j = 0; j < EPT; ++j) {
        if (dv[j] >= 0) {
            int pos = lh[dv[j] >> BSH] + rv[j];
            pairs[pos] = ((unsigned long long)(unsigned)dv[j] << 32) | (unsigned)sv[j];
        }
    }
}

__global__ void k_bcount(const unsigned long long* __restrict__ pairs,
                         const int* __restrict__ bstart, int* __restrict__ cnt) {
    __shared__ int lc[256];
    int b = blockIdx.x, tid = threadIdx.x;
    lc[tid] = 0;
    __syncthreads();
    int s0 = bstart[b], s1 = bstart[b + 1];
    int nbase = b << BSH;
    for (int e = s0 + tid; e < s1; e += 256)
        atomicAdd(&lc[(int)(pairs[e] >> 32) - nbase], 1);
    __syncthreads();
    int node = nbase + tid;
    if (node < N_NODES) cnt[node] = lc[tid];
}

__global__ void k_scan_blk(const int* __restrict__ cnt, int* __restrict__ cursor,
                           int* __restrict__ blks) {
    __shared__ int s[256];
    int tid = threadIdx.x;
    int base = blockIdx.x * SCAN_ITEMS + tid * 4;
    int a0 = (base + 0 < N_NODES) ? cnt[base + 0] : 0;
    int a1 = (base + 1 < N_NODES) ? cnt[base + 1] : 0;
    int a2 = (base + 2 < N_NODES) ? cnt[base + 2] : 0;
    int a3 = (base + 3 < N_NODES) ? cnt[base + 3] : 0;
    int tsum = a0 + a1 + a2 + a3;
    s[tid] = tsum;
    __syncthreads();
    for (int off = 1; off < 256; off <<= 1) {
        int t = (tid >= off) ? s[tid - off] : 0;
        __syncthreads();
        s[tid] += t;
        __syncthreads();
    }
    int texcl = s[tid] - tsum;
    if (base + 0 < N_NODES) cursor[base + 0] = texcl;
    if (base + 1 < N_NODES) cursor[base + 1] = texcl + a0;
    if (base + 2 < N_NODES) cursor[base + 2] = texcl + a0 + a1;
    if (base + 3 < N_NODES) cursor[base + 3] = texcl + a0 + a1 + a2;
    if (tid == 0) blks[blockIdx.x] = s[255];
}

__global__ void k_scan_top(int* __restrict__ blks) {
    __shared__ int s[128];
    int tid = threadIdx.x;
    int v = (tid < NB) ? blks[tid] : 0;
    s[tid] = v;
    __syncthreads();
    for (int off = 1; off < 128; off <<= 1) {
        int t = (tid >= off) ? s[tid - off] : 0;
        __syncthreads();
        s[tid] += t;
        __syncthreads();
    }
    if (tid < NB) blks[tid] = s[tid] - v;
}

__global__ void k_scan_add(const int* __restrict__ cnt, int* __restrict__ cursor,
                           const int* __restrict__ blks, float* __restrict__ dinv) {
    int tid = threadIdx.x;
    int base = blockIdx.x * SCAN_ITEMS + tid * 4;
    int off = blks[blockIdx.x];
#pragma unroll
    for (int j = 0; j < 4; ++j) {
        int i = base + j;
        if (i < N_NODES) {
            cursor[i] += off;
            dinv[i] = rsqrtf(1.0f + (float)cnt[i]);
        }
    }
}

__global__ void k_bfill(const unsigned long long* __restrict__ pairs,
                        const int* __restrict__ bstart, const int* __restrict__ cursor,
                        int* __restrict__ esrc) {
    __shared__ int lcur[256];
    int b = blockIdx.x, tid = threadIdx.x;
    int nbase = b << BSH;
    int node = nbase + tid;
    lcur[tid] = (node < N_NODES) ? cursor[node] : 0;
    __syncthreads();
    int s0 = bstart[b], s1 = bstart[b + 1];
    for (int e = s0 + tid; e < s1; e += 256) {
        unsigned long long p = pairs[e];
        int d = (int)(p >> 32);
        int s = (int)(p & 0xffffffffu);
        int pos = atomicAdd(&lcur[d - nbase], 1);
        esrc[pos] = s;
    }
}

// ---------------------------------------------------------------------------
// MFMA GEMM1: g1[n,c] = fp16( dinv[n] * (x[n,:] @ W1)[c] )
// One wave per 16-row strip-pair; B (all of W1) held in 64 VGPRs.
// A-frags read straight from global x (coalesced 128B/row), cvt to fp16.
// Layout-safe: A and B use identical per-lane k distribution, so the MFMA
// k-pairing is invariant to the exact hardware k map.
// ---------------------------------------------------------------------------
__global__ void k_gemm1_mfma(const float* __restrict__ x, const half_t* __restrict__ W1T,
                             const float* __restrict__ dinv, half_t* __restrict__ g1) {
    int lane = threadIdx.x & 63;
    int l16  = lane & 15;
    int lg   = lane >> 4;

    // B fragments: bf[ct][kc]; lane holds col n = ct*16+l16, k = kc*32 + lg*8 + i
    half8 bf[4][4];
#pragma unroll
    for (int ct = 0; ct < 4; ++ct)
#pragma unroll
        for (int kc = 0; kc < 4; ++kc)
            bf[ct][kc] = *(const half8*)(W1T + (ct * 16 + l16) * IN_C + kc * 32 + lg * 8);

#pragma unroll
    for (int s = 0; s < 2; ++s) {
        int r0 = (blockIdx.x * 2 + s) * 16;
        f32x4 acc0 = {0.f, 0.f, 0.f, 0.f};
        f32x4 acc1 = {0.f, 0.f, 0.f, 0.f};
        f32x4 acc2 = {0.f, 0.f, 0.f, 0.f};
        f32x4 acc3 = {0.f, 0.f, 0.f, 0.f};
#pragma unroll
        for (int kc = 0; kc < 4; ++kc) {
            const float* ap = x + (size_t)(r0 + l16) * IN_C + kc * 32 + lg * 8;
            float4 a0 = *(const float4*)ap;
            float4 a1 = *(const float4*)(ap + 4);
            half8 af;
            af[0] = (_Float16)a0.x; af[1] = (_Float16)a0.y;
            af[2] = (_Float16)a0.z; af[3] = (_Float16)a0.w;
            af[4] = (_Float16)a1.x; af[5] = (_Float16)a1.y;
            af[6] = (_Float16)a1.z; af[7] = (_Float16)a1.w;
            acc0 = __builtin_amdgcn_mfma_f32_16x16x32_f16(af, bf[0][kc], acc0, 0, 0, 0);
            acc1 = __builtin_amdgcn_mfma_f32_16x16x32_f16(af, bf[1][kc], acc1, 0, 0, 0);
            acc2 = __builtin_amdgcn_mfma_f32_16x16x32_f16(af, bf[2][kc], acc2, 0, 0, 0);
            acc3 = __builtin_amdgcn_mfma_f32_16x16x32_f16(af, bf[3][kc], acc3, 0, 0, 0);
        }
        // C/D layout (HW-verified): col = lane&15, row = (lane>>4)*4 + reg
        float dv[4];
#pragma unroll
        for (int j = 0; j < 4; ++j) dv[j] = dinv[r0 + lg * 4 + j];
#pragma unroll
        for (int j = 0; j < 4; ++j) {
            size_t rb = (size_t)(r0 + lg * 4 + j) * HID_C;
            g1[rb +  0 + l16] = (half_t)(acc0[j] * dv[j]);
            g1[rb + 16 + l16] = (half_t)(acc1[j] * dv[j]);
            g1[rb + 32 + l16] = (half_t)(acc2[j] * dv[j]);
            g1[rb + 48 + l16] = (half_t)(acc3[j] * dv[j]);
        }
    }
}

// ---------------------------------------------------------------------------
// pull layer1 + fused 64->40 GEMM (fp16 gathers, fp32 math)
// ---------------------------------------------------------------------------
__global__ void k_pull1(const int* __restrict__ cursor, const int* __restrict__ cnt,
                        const int* __restrict__ esrc, const float* __restrict__ dinv,
                        const half_t* __restrict__ g1, const float* __restrict__ b1,
                        const float* __restrict__ W2, half_t* __restrict__ g2) {
    __shared__ float lds[4][HID_C];
    int w    = threadIdx.x >> 6;
    int lane = threadIdx.x & 63;
    int n    = blockIdx.x * 4 + w;
    float dn  = dinv[n];
    int start = cursor[n];
    int end   = start + cnt[n];
    float acc = (float)g1[(size_t)n * HID_C + lane];
    int e = start;
    for (; e + 3 < end; e += 4) {
        int s0 = esrc[e], s1 = esrc[e + 1], s2 = esrc[e + 2], s3 = esrc[e + 3];
        float v0 = (float)g1[(size_t)s0 * HID_C + lane];
        float v1 = (float)g1[(size_t)s1 * HID_C + lane];
        float v2 = (float)g1[(size_t)s2 * HID_C + lane];
        float v3 = (float)g1[(size_t)s3 * HID_C + lane];
        acc += v0 + v1 + v2 + v3;
    }
    for (; e < end; ++e)
        acc += (float)g1[(size_t)esrc[e] * HID_C + lane];
    float r = fmaxf(dn * acc + b1[lane], 0.0f);
    lds[w][lane] = r;
    if (lane < OUT_C) {
        float s = 0.0f;
#pragma unroll
        for (int c = 0; c < HID_C; ++c)
            s += lds[w][c] * W2[c * OUT_C + lane];
        g2[(size_t)n * OUT_C + lane] = (half_t)(dn * s);
    }
}

// ---------------------------------------------------------------------------
// pull layer2 -> out (fp32)
// ---------------------------------------------------------------------------
__global__ void k_pull2(const int* __restrict__ cursor, const int* __restrict__ cnt,
                        const int* __restrict__ esrc, const float* __restrict__ dinv,
                        const half_t* __restrict__ g2, const float* __restrict__ b2,
                        float* __restrict__ out) {
    int w    = threadIdx.x >> 6;
    int lane = threadIdx.x & 63;
    int n    = blockIdx.x * 4 + w;
    if (lane >= OUT_C) return;
    float dn  = dinv[n];
    int start = cursor[n];
    int end   = start + cnt[n];
    float acc = (float)g2[(size_t)n * OUT_C + lane];
    int e = start;
    for (; e + 3 < end; e += 4) {
        int s0 = esrc[e], s1 = esrc[e + 1], s2 = esrc[e + 2], s3 = esrc[e + 3];
        float v0 = (float)g2[(size_t)s0 * OUT_C + lane];
        float v1 = (float)g2[(size_t)s1 * OUT_C + lane];
        float v2 = (float)g2[(size_t)s2 * OUT_C + lane];
        float v3 = (float)g2[(size_t)s3 * OUT_C + lane];
        acc += v0 + v1 + v2 + v3;
    }
    for (; e < end; ++e)
        acc += (float)g2[(size_t)esrc[e] * OUT_C + lane];
    out[(size_t)n * OUT_C + lane] = b2[lane] + dn * acc;
}

// ---------------------------------------------------------------------------
// launch
// ---------------------------------------------------------------------------
extern "C" void kernel_launch(void* const* d_in, const int* in_sizes, int n_in,
                              void* d_out, int out_size, void* d_ws, size_t ws_size,
                              hipStream_t stream) {
    const float* x   = (const float*)d_in[0];
    const int*   ei  = (const int*)d_in[1];
    const int*   src = ei;
    const int*   dst = ei + N_EDGES;
    const float* W1  = (const float*)d_in[2];
    const float* b1  = (const float*)d_in[3];
    const float* W2  = (const float*)d_in[4];
    const float* b2  = (const float*)d_in[5];
    float*       out = (float*)d_out;

    // workspace layout
    int*    cnt    = (int*)d_ws;                      // N
    int*    cursor = cnt + N_NODES;                   // N
    int*    blks   = cursor + N_NODES;                // 128
    int*    bcnt   = blks + 128;                      // NBUCK
    int*    bstart = bcnt + NBUCK;                    // NBUCK+1
    int*    gcur   = bstart + NBUCK + 1;              // NBUCK
    half_t* w1t    = (half_t*)(gcur + NBUCK);         // 128*64 halves (16KB)
    float*  dinv   = (float*)(w1t + IN_C * HID_C);    // N
    int*    esrc   = (int*)(dinv + N_NODES);          // E
    int*    after  = esrc + N_EDGES;
    unsigned long long* pairs =
        (unsigned long long*)(((uintptr_t)after + 7) & ~(uintptr_t)7);  // E * 8B
    half_t* g1 = (half_t*)pairs;                      // overlays pairs (12.8MB each)
    half_t* g2 = (half_t*)(pairs + N_EDGES);          // N*OUT_C halves

    const int B = 256;

    // CSR build (bucketed)
    k_init<<<1, 512, 0, stream>>>(W1, w1t, bcnt);
    k_hist<<<NPB, 256, 0, stream>>>(dst, bcnt);
    k_bscan<<<1, 512, 0, stream>>>(bcnt, bstart, gcur);
    k_part<<<NPB, 256, 0, stream>>>(src, dst, gcur, pairs);
    k_bcount<<<NBUCK, 256, 0, stream>>>(pairs, bstart, cnt);
    k_scan_blk<<<NB, 256, 0, stream>>>(cnt, cursor, blks);
    k_scan_top<<<1, 128, 0, stream>>>(blks);
    k_scan_add<<<NB, 256, 0, stream>>>(cnt, cursor, blks, dinv);
    k_bfill<<<NBUCK, 256, 0, stream>>>(pairs, bstart, cursor, esrc);

    // layer 1 transform: g1 = dinv * (x @ W1)  [fp16, MFMA]
    k_gemm1_mfma<<<N_NODES / 32, 64, 0, stream>>>(x, w1t, dinv, g1);

    // pull layer 1 + fused GEMM2
    k_pull1<<<N_NODES / 4, 256, 0, stream>>>(cursor, cnt, esrc, dinv, g1, b1, W2, g2);

    // pull layer 2
    k_pull2<<<N_NODES / 4, 256, 0, stream>>>(cursor, cnt, esrc, dinv, g2, b2, out);
}

// Round 5
// 223.597 us; speedup vs baseline: 4.4168x; 1.1316x over previous
//
#include <hip/hip_runtime.h>

#define N_NODES 100000
#define IN_C    128
#define HID_C   64
#define OUT_C   40
#define N_EDGES 1600000

// bucketed CSR build
#define BSH        8
#define NBUCK      ((N_NODES + 255) >> BSH)              // 391 buckets of 256 nodes
#define PART_CHUNK 4096
#define NPB        ((N_EDGES + PART_CHUNK - 1) / PART_CHUNK)  // 391
#define EPT        (PART_CHUNK / 256)

// node-count scan
#define SCAN_ITEMS 1024
#define NB ((N_NODES + SCAN_ITEMS - 1) / SCAN_ITEMS)     // 98

typedef _Float16 half_t;
typedef _Float16 half8  __attribute__((ext_vector_type(8)));
typedef _Float16 half2_t __attribute__((ext_vector_type(2)));
typedef float    f32x4  __attribute__((ext_vector_type(4)));

static __device__ __forceinline__ void acc_pair(float2& a, unsigned v) {
    half2_t h = __builtin_bit_cast(half2_t, v);
    a.x += (float)h.x;
    a.y += (float)h.y;
}

// ---------------------------------------------------------------------------
// init: zero bucket counts + transpose W1 -> W1T [64][128] fp16
// ---------------------------------------------------------------------------
__global__ void k_init(const float* __restrict__ W1, half_t* __restrict__ W1T,
                       int* __restrict__ bcnt) {
    int t = threadIdx.x;  // 512
    if (t < NBUCK) bcnt[t] = 0;
    for (int i = t; i < IN_C * HID_C; i += 512) {
        int k = i >> 6, n = i & 63;
        W1T[n * IN_C + k] = (half_t)W1[i];
    }
}

__global__ void k_hist(const int* __restrict__ dst, int* __restrict__ bcnt) {
    __shared__ int lh[NBUCK];
    int tid = threadIdx.x;
    for (int i = tid; i < NBUCK; i += 256) lh[i] = 0;
    __syncthreads();
    int base = blockIdx.x * PART_CHUNK;
#pragma unroll
    for (int j = 0; j < EPT; ++j) {
        int e = base + j * 256 + tid;
        if (e < N_EDGES) atomicAdd(&lh[dst[e] >> BSH], 1);
    }
    __syncthreads();
    for (int i = tid; i < NBUCK; i += 256)
        if (lh[i]) atomicAdd(&bcnt[i], lh[i]);
}

__global__ void k_bscan(const int* __restrict__ bcnt, int* __restrict__ bstart,
                        int* __restrict__ gcur) {
    __shared__ int s[512];
    int tid = threadIdx.x;
    int v = (tid < NBUCK) ? bcnt[tid] : 0;
    s[tid] = v;
    __syncthreads();
    for (int off = 1; off < 512; off <<= 1) {
        int t = (tid >= off) ? s[tid - off] : 0;
        __syncthreads();
        s[tid] += t;
        __syncthreads();
    }
    if (tid < NBUCK) {
        int excl = s[tid] - v;
        bstart[tid] = excl;
        gcur[tid]   = excl;
    }
    if (tid == 0) bstart[NBUCK] = N_EDGES;
}

__global__ void k_part(const int* __restrict__ src, const int* __restrict__ dst,
                       int* __restrict__ gcur, unsigned long long* __restrict__ pairs) {
    __shared__ int lh[NBUCK];
    int tid = threadIdx.x;
    for (int i = tid; i < NBUCK; i += 256) lh[i] = 0;
    __syncthreads();
    int base = blockIdx.x * PART_CHUNK;
    int sv[EPT], dv[EPT], rv[EPT];
#pragma unroll
    for (int j = 0; j < EPT; ++j) {
        int e = base + j * 256 + tid;
        if (e < N_EDGES) {
            sv[j] = src[e];
            dv[j] = dst[e];
            rv[j] = atomicAdd(&lh[dv[j] >> BSH], 1);
        } else {
            dv[j] = -1;
        }
    }
    __syncthreads();
    for (int i = tid; i < NBUCK; i += 256) {
        int c = lh[i];
        if (c) lh[i] = atomicAdd(&gcur[i], c);
    }
    __syncthreads();
#pragma unroll
    for (int j = 0; j < EPT; ++j) {
        if (dv[j] >= 0) {
            int pos = lh[dv[j] >> BSH] + rv[j];
            pairs[pos] = ((unsigned long long)(unsigned)dv[j] << 32) | (unsigned)sv[j];
        }
    }
}

__global__ void k_bcount(const unsigned long long* __restrict__ pairs,
                         const int* __restrict__ bstart, int* __restrict__ cnt) {
    __shared__ int lc[256];
    int b = blockIdx.x, tid = threadIdx.x;
    lc[tid] = 0;
    __syncthreads();
    int s0 = bstart[b], s1 = bstart[b + 1];
    int nbase = b << BSH;
    for (int e = s0 + tid; e < s1; e += 256)
        atomicAdd(&lc[(int)(pairs[e] >> 32) - nbase], 1);
    __syncthreads();
    int node = nbase + tid;
    if (node < N_NODES) cnt[node] = lc[tid];
}

__global__ void k_scan_blk(const int* __restrict__ cnt, int* __restrict__ cursor,
                           int* __restrict__ blks) {
    __shared__ int s[256];
    int tid = threadIdx.x;
    int base = blockIdx.x * SCAN_ITEMS + tid * 4;
    int a0 = (base + 0 < N_NODES) ? cnt[base + 0] : 0;
    int a1 = (base + 1 < N_NODES) ? cnt[base + 1] : 0;
    int a2 = (base + 2 < N_NODES) ? cnt[base + 2] : 0;
    int a3 = (base + 3 < N_NODES) ? cnt[base + 3] : 0;
    int tsum = a0 + a1 + a2 + a3;
    s[tid] = tsum;
    __syncthreads();
    for (int off = 1; off < 256; off <<= 1) {
        int t = (tid >= off) ? s[tid - off] : 0;
        __syncthreads();
        s[tid] += t;
        __syncthreads();
    }
    int texcl = s[tid] - tsum;
    if (base + 0 < N_NODES) cursor[base + 0] = texcl;
    if (base + 1 < N_NODES) cursor[base + 1] = texcl + a0;
    if (base + 2 < N_NODES) cursor[base + 2] = texcl + a0 + a1;
    if (base + 3 < N_NODES) cursor[base + 3] = texcl + a0 + a1 + a2;
    if (tid == 0) blks[blockIdx.x] = s[255];
}

__global__ void k_scan_top(int* __restrict__ blks) {
    __shared__ int s[128];
    int tid = threadIdx.x;
    int v = (tid < NB) ? blks[tid] : 0;
    s[tid] = v;
    __syncthreads();
    for (int off = 1; off < 128; off <<= 1) {
        int t = (tid >= off) ? s[tid - off] : 0;
        __syncthreads();
        s[tid] += t;
        __syncthreads();
    }
    if (tid < NB) blks[tid] = s[tid] - v;
}

__global__ void k_scan_add(const int* __restrict__ cnt, int* __restrict__ cursor,
                           const int* __restrict__ blks, float* __restrict__ dinv) {
    int tid = threadIdx.x;
    int base = blockIdx.x * SCAN_ITEMS + tid * 4;
    int off = blks[blockIdx.x];
#pragma unroll
    for (int j = 0; j < 4; ++j) {
        int i = base + j;
        if (i < N_NODES) {
            cursor[i] += off;
            dinv[i] = rsqrtf(1.0f + (float)cnt[i]);
        }
    }
}

__global__ void k_bfill(const unsigned long long* __restrict__ pairs,
                        const int* __restrict__ bstart, const int* __restrict__ cursor,
                        int* __restrict__ esrc) {
    __shared__ int lcur[256];
    int b = blockIdx.x, tid = threadIdx.x;
    int nbase = b << BSH;
    int node = nbase + tid;
    lcur[tid] = (node < N_NODES) ? cursor[node] : 0;
    __syncthreads();
    int s0 = bstart[b], s1 = bstart[b + 1];
    for (int e = s0 + tid; e < s1; e += 256) {
        unsigned long long p = pairs[e];
        int d = (int)(p >> 32);
        int s = (int)(p & 0xffffffffu);
        int pos = atomicAdd(&lcur[d - nbase], 1);
        esrc[pos] = s;
    }
}

// ---------------------------------------------------------------------------
// MFMA GEMM1: g1[n,c] = fp16( dinv[n] * (x[n,:] @ W1)[c] )
// ---------------------------------------------------------------------------
__global__ void k_gemm1_mfma(const float* __restrict__ x, const half_t* __restrict__ W1T,
                             const float* __restrict__ dinv, half_t* __restrict__ g1) {
    int lane = threadIdx.x & 63;
    int l16  = lane & 15;
    int lg   = lane >> 4;

    half8 bf[4][4];
#pragma unroll
    for (int ct = 0; ct < 4; ++ct)
#pragma unroll
        for (int kc = 0; kc < 4; ++kc)
            bf[ct][kc] = *(const half8*)(W1T + (ct * 16 + l16) * IN_C + kc * 32 + lg * 8);

#pragma unroll
    for (int s = 0; s < 2; ++s) {
        int r0 = (blockIdx.x * 2 + s) * 16;
        f32x4 acc0 = {0.f, 0.f, 0.f, 0.f};
        f32x4 acc1 = {0.f, 0.f, 0.f, 0.f};
        f32x4 acc2 = {0.f, 0.f, 0.f, 0.f};
        f32x4 acc3 = {0.f, 0.f, 0.f, 0.f};
#pragma unroll
        for (int kc = 0; kc < 4; ++kc) {
            const float* ap = x + (size_t)(r0 + l16) * IN_C + kc * 32 + lg * 8;
            float4 a0 = *(const float4*)ap;
            float4 a1 = *(const float4*)(ap + 4);
            half8 af;
            af[0] = (_Float16)a0.x; af[1] = (_Float16)a0.y;
            af[2] = (_Float16)a0.z; af[3] = (_Float16)a0.w;
            af[4] = (_Float16)a1.x; af[5] = (_Float16)a1.y;
            af[6] = (_Float16)a1.z; af[7] = (_Float16)a1.w;
            acc0 = __builtin_amdgcn_mfma_f32_16x16x32_f16(af, bf[0][kc], acc0, 0, 0, 0);
            acc1 = __builtin_amdgcn_mfma_f32_16x16x32_f16(af, bf[1][kc], acc1, 0, 0, 0);
            acc2 = __builtin_amdgcn_mfma_f32_16x16x32_f16(af, bf[2][kc], acc2, 0, 0, 0);
            acc3 = __builtin_amdgcn_mfma_f32_16x16x32_f16(af, bf[3][kc], acc3, 0, 0, 0);
        }
        float dv[4];
#pragma unroll
        for (int j = 0; j < 4; ++j) dv[j] = dinv[r0 + lg * 4 + j];
#pragma unroll
        for (int j = 0; j < 4; ++j) {
            size_t rb = (size_t)(r0 + lg * 4 + j) * HID_C;
            g1[rb +  0 + l16] = (half_t)(acc0[j] * dv[j]);
            g1[rb + 16 + l16] = (half_t)(acc1[j] * dv[j]);
            g1[rb + 32 + l16] = (half_t)(acc2[j] * dv[j]);
            g1[rb + 48 + l16] = (half_t)(acc3[j] * dv[j]);
        }
    }
}

// ---------------------------------------------------------------------------
// pull layer1 + fused 64->40 GEMM.
// Wave = 1 node; two 32-lane halves each gather a different edge's row as
// uint (2xfp16) -> 1 load instr covers 2 edges (256B). fp32 accumulate.
// ---------------------------------------------------------------------------
__global__ void k_pull1(const int* __restrict__ cursor, const int* __restrict__ cnt,
                        const int* __restrict__ esrc, const float* __restrict__ dinv,
                        const half_t* __restrict__ g1, const float* __restrict__ b1,
                        const float* __restrict__ W2, half_t* __restrict__ g2) {
    __shared__ float lds[4][HID_C];
    int w    = threadIdx.x >> 6;
    int lane = threadIdx.x & 63;
    int n    = blockIdx.x * 4 + w;
    int h    = lane >> 5;    // edge slot within wave
    int c2   = lane & 31;    // channel pair
    const unsigned* g1u = (const unsigned*)g1;

    float dn  = dinv[n];
    int start = cursor[n];
    int end   = start + cnt[n];

    float2 acc = {0.f, 0.f};
    if (h == 0) acc_pair(acc, g1u[(size_t)n * 32 + c2]);  // self row

    int e = start + h;
    for (; e + 6 < end; e += 8) {
        int s0 = esrc[e], s1 = esrc[e + 2], s2 = esrc[e + 4], s3 = esrc[e + 6];
        unsigned v0 = g1u[(size_t)s0 * 32 + c2];
        unsigned v1 = g1u[(size_t)s1 * 32 + c2];
        unsigned v2 = g1u[(size_t)s2 * 32 + c2];
        unsigned v3 = g1u[(size_t)s3 * 32 + c2];
        acc_pair(acc, v0); acc_pair(acc, v1); acc_pair(acc, v2); acc_pair(acc, v3);
    }
    for (; e < end; e += 2)
        acc_pair(acc, g1u[(size_t)esrc[e] * 32 + c2]);

    // combine halves
    acc.x += __shfl_xor(acc.x, 32);
    acc.y += __shfl_xor(acc.y, 32);

    if (h == 0) {
        float2 bb = ((const float2*)b1)[c2];
        lds[w][2 * c2 + 0] = fmaxf(dn * acc.x + bb.x, 0.0f);
        lds[w][2 * c2 + 1] = fmaxf(dn * acc.y + bb.y, 0.0f);
    }
    // wave-private LDS; same-wave write->read ordering handled by compiler
    if (lane < OUT_C) {
        float s = 0.0f;
#pragma unroll
        for (int c = 0; c < HID_C; ++c)
            s += lds[w][c] * W2[c * OUT_C + lane];
        g2[(size_t)n * OUT_C + lane] = (half_t)(dn * s);
    }
}

// ---------------------------------------------------------------------------
// pull layer2 -> out. 3 edges per wave (20 lanes x 4B = 80B row each).
// ---------------------------------------------------------------------------
__global__ void k_pull2(const int* __restrict__ cursor, const int* __restrict__ cnt,
                        const int* __restrict__ esrc, const float* __restrict__ dinv,
                        const half_t* __restrict__ g2, const float* __restrict__ b2,
                        float* __restrict__ out) {
    int w    = threadIdx.x >> 6;
    int lane = threadIdx.x & 63;
    int n    = blockIdx.x * 4 + w;
    int slot = lane / 20;            // 0..2 active, 3 idle
    int c2   = lane - slot * 20;     // channel pair 0..19
    const unsigned* g2u = (const unsigned*)g2;

    float dn  = dinv[n];
    int start = cursor[n];
    int end   = start + cnt[n];

    float2 acc = {0.f, 0.f};
    if (slot == 0) acc_pair(acc, g2u[(size_t)n * 20 + c2]);  // self row

    if (slot < 3) {
        int e = start + slot;
        for (; e + 9 < end; e += 12) {
            int s0 = esrc[e], s1 = esrc[e + 3], s2 = esrc[e + 6], s3 = esrc[e + 9];
            unsigned v0 = g2u[(size_t)s0 * 20 + c2];
            unsigned v1 = g2u[(size_t)s1 * 20 + c2];
            unsigned v2 = g2u[(size_t)s2 * 20 + c2];
            unsigned v3 = g2u[(size_t)s3 * 20 + c2];
            acc_pair(acc, v0); acc_pair(acc, v1); acc_pair(acc, v2); acc_pair(acc, v3);
        }
        for (; e < end; e += 3)
            acc_pair(acc, g2u[(size_t)esrc[e] * 20 + c2]);
    }

    // combine 3 slots (all lanes execute the shuffles)
    float x1 = __shfl(acc.x, c2 + 20);
    float y1 = __shfl(acc.y, c2 + 20);
    float x2 = __shfl(acc.x, c2 + 40);
    float y2 = __shfl(acc.y, c2 + 40);
    if (slot == 0) {
        float2 bb = ((const float2*)b2)[c2];
        float2 r;
        r.x = bb.x + dn * (acc.x + x1 + x2);
        r.y = bb.y + dn * (acc.y + y1 + y2);
        ((float2*)(out + (size_t)n * OUT_C))[c2] = r;
    }
}

// ---------------------------------------------------------------------------
// launch
// ---------------------------------------------------------------------------
extern "C" void kernel_launch(void* const* d_in, const int* in_sizes, int n_in,
                              void* d_out, int out_size, void* d_ws, size_t ws_size,
                              hipStream_t stream) {
    const float* x   = (const float*)d_in[0];
    const int*   ei  = (const int*)d_in[1];
    const int*   src = ei;
    const int*   dst = ei + N_EDGES;
    const float* W1  = (const float*)d_in[2];
    const float* b1  = (const float*)d_in[3];
    const float* W2  = (const float*)d_in[4];
    const float* b2  = (const float*)d_in[5];
    float*       out = (float*)d_out;

    // workspace layout
    int*    cnt    = (int*)d_ws;                      // N
    int*    cursor = cnt + N_NODES;                   // N
    int*    blks   = cursor + N_NODES;                // 128
    int*    bcnt   = blks + 128;                      // NBUCK
    int*    bstart = bcnt + NBUCK;                    // NBUCK+1
    int*    gcur   = bstart + NBUCK + 1;              // NBUCK
    half_t* w1t    = (half_t*)(gcur + NBUCK);         // 128*64 halves (16KB)
    float*  dinv   = (float*)(w1t + IN_C * HID_C);    // N
    int*    esrc   = (int*)(dinv + N_NODES);          // E
    int*    after  = esrc + N_EDGES;
    unsigned long long* pairs =
        (unsigned long long*)(((uintptr_t)after + 7) & ~(uintptr_t)7);  // E * 8B
    half_t* g1 = (half_t*)pairs;                      // overlays pairs
    half_t* g2 = (half_t*)(pairs + N_EDGES);          // N*OUT_C halves

    // CSR build (bucketed)
    k_init<<<1, 512, 0, stream>>>(W1, w1t, bcnt);
    k_hist<<<NPB, 256, 0, stream>>>(dst, bcnt);
    k_bscan<<<1, 512, 0, stream>>>(bcnt, bstart, gcur);
    k_part<<<NPB, 256, 0, stream>>>(src, dst, gcur, pairs);
    k_bcount<<<NBUCK, 256, 0, stream>>>(pairs, bstart, cnt);
    k_scan_blk<<<NB, 256, 0, stream>>>(cnt, cursor, blks);
    k_scan_top<<<1, 128, 0, stream>>>(blks);
    k_scan_add<<<NB, 256, 0, stream>>>(cnt, cursor, blks, dinv);
    k_bfill<<<NBUCK, 256, 0, stream>>>(pairs, bstart, cursor, esrc);

    // layer 1 transform: g1 = dinv * (x @ W1)  [fp16, MFMA]
    k_gemm1_mfma<<<N_NODES / 32, 64, 0, stream>>>(x, w1t, dinv, g1);

    // pull layer 1 + fused GEMM2
    k_pull1<<<N_NODES / 4, 256, 0, stream>>>(cursor, cnt, esrc, dinv, g1, b1, W2, g2);

    // pull layer 2
    k_pull2<<<N_NODES / 4, 256, 0, stream>>>(cursor, cnt, esrc, dinv, g2, b2, out);
}